// Round 10
// baseline (119.229 us; speedup 1.0000x reference)
//
#include <hip/hip_runtime.h>
#include <hip/hip_fp8.h>
#include <hip/hip_fp16.h>
#include <stdint.h>

#define MARGIN 0.3f

constexpr int N = 8192;
constexpr int D = 512;
constexpr int BM = 128, BN = 128;
constexpr int NKS = D / 64;                   // 8 K-steps of 64
constexpr int NKP = NKS / 2;                  // 4 K-step PAIRS (BK=128)
constexpr int NT = N / BM;                    // 64 tiles per side
constexpr int NPAIR = NT * (NT + 1) / 2;      // 2080 unordered tile pairs
constexpr int WEDGE = NPAIR / 8;              // 260 pairs per XCD wedge
constexpr float ESCALE = 16.0f;               // fp8 pre-scale
constexpr float INV_SC2 = 1.0f / (ESCALE * ESCALE);  // exact pow2: defer to finalize

typedef int i32x8 __attribute__((ext_vector_type(8)));
typedef float f32x16 __attribute__((ext_vector_type(16)));
typedef __fp16 h2 __attribute__((ext_vector_type(2)));

constexpr unsigned INF2 = 0x7C007C00u;  // packed f16 (+inf, +inf)

__device__ __forceinline__ unsigned char f2fp8(float f) {
  return __hip_fp8_e4m3(f).__x;  // OCP e4m3fn, RNE+sat
}

// packed-f16 min: lo tracks min(pos-sim), hi tracks min(-neg-sim) == -max(neg-sim)
__device__ __forceinline__ unsigned pkmin(unsigned a, unsigned b) {
  unsigned d;
  asm("v_pk_min_f16 %0, %1, %2" : "=v"(d) : "v"(a), "v"(b));
  return d;
}

__device__ __forceinline__ unsigned cvtpk(float lo, float hi) {
  union { h2 h; unsigned u; } cv;
  cv.h = __builtin_amdgcn_cvt_pkrtz(lo, hi);  // RTZ, monotone => mining-safe
  return cv.u;
}

// Decode pair index q (super-tile-major enumeration of the lower triangle)
// into (ti, tj), ti >= tj. Super-tile = 8x8 tiles; base(SI) = 32*SI^2 + 4*SI.
__device__ __forceinline__ void pair_from_q(int q, int& ti, int& tj) {
  int SI = 0;
  while (32 * (SI + 1) * (SI + 1) + 4 * (SI + 1) <= q) ++SI;
  int r = q - (32 * SI * SI + 4 * SI);
  int i, j, SJ;
  if (r < 64 * SI) {
    SJ = r >> 6;
    int w = r & 63;
    i = w >> 3;
    j = w & 7;
  } else {
    int d = r - 64 * SI;
    SJ = SI;
    i = 0;
    while ((i + 1) * (i + 2) / 2 <= d) ++i;
    j = d - i * (i + 1) / 2;
  }
  ti = SI * 8 + i;
  tj = SJ * 8 + j;
}

// e8 layout: 32-row groups g = row>>5, K-steps T = k>>6 (stored-k; the k
// permutation from normalize's lane packing is row-uniform so dots are
// preserved). Block (g,T) = 2048 B at (g*8+T)*2048. Within a block, byte
// (n=row&31, k'=k&63) lives at
//   ((n*64 + (((k'>>4)&3)<<4)) ^ (((n>>1)&7)<<4)) + (k'&15)
// XOR swizzle spreads wave ds_read_b128 of MFMA fragments across banks;
// global_load_lds copies blocks LINEARLY so the swizzle survives.

// ---- kernel 1: L2-normalize rows -> fp8 e4m3 (x16), swizzled block layout --
__global__ __launch_bounds__(256) void normalize_rows(
    const float* __restrict__ emb, unsigned char* __restrict__ e8,
    float* __restrict__ out) {
  if (blockIdx.x == 0 && threadIdx.x == 0) out[0] = 0.f;
  const int wave = threadIdx.x >> 6, lane = threadIdx.x & 63;
  const int row = blockIdx.x * 4 + wave;
  const float4* src = (const float4*)(emb + (size_t)row * D);
  float4 x0 = src[lane];
  float4 x1 = src[lane + 64];
  float ss = x0.x * x0.x + x0.y * x0.y + x0.z * x0.z + x0.w * x0.w +
             x1.x * x1.x + x1.y * x1.y + x1.z * x1.z + x1.w * x1.w;
#pragma unroll
  for (int m = 1; m < 64; m <<= 1) ss += __shfl_xor(ss, m, 64);
  const float r = rsqrtf(ss) * ESCALE;
  union { unsigned char b[8]; unsigned long long u; } o;
  o.b[0] = f2fp8(x0.x * r); o.b[1] = f2fp8(x0.y * r);
  o.b[2] = f2fp8(x0.z * r); o.b[3] = f2fp8(x0.w * r);
  o.b[4] = f2fp8(x1.x * r); o.b[5] = f2fp8(x1.y * r);
  o.b[6] = f2fp8(x1.z * r); o.b[7] = f2fp8(x1.w * r);
  // stored-k for this thread: k = lane*8 .. +7
  const int n = row & 31;
  const unsigned inner =
      ((unsigned)(n * 64 + ((lane >> 1) & 3) * 16) ^
       ((unsigned)((n >> 1) & 7) << 4)) + (lane & 1) * 8;
  const unsigned off = (unsigned)((row >> 5) * 8 + (lane >> 3)) * 2048 + inner;
  *(unsigned long long*)(e8 + off) = o.u;
}

// ---- kernel 2: MX-fp8 (scale=1) symmetric Gram GEMM + batch-hard mining ----
// 2080 blocks (pair q = 260*(b%8) + b/8, XCD-wedge). BK=128 LDS staging:
// 2 K-steps per barrier (4 drains per block instead of 8); 64KB double
// buffer fits the measured 2-blocks/CU residency. 32x32x64 f8f6f4 MFMA at
// the MX rate; packed-f16 mining epilogue with ds_swizzle butterflies.
__global__ __launch_bounds__(256, 2) void bh_gemm_sym(
    const unsigned char* __restrict__ e8, const int* __restrict__ labels,
    unsigned* __restrict__ scr) {
  __shared__ unsigned char lds[2][2][16384];  // [buf][sub-K][A 8KB | B 8KB]
  __shared__ unsigned bufR[2][128];           // [wc][row within tile]
  __shared__ unsigned bufC[2][128];           // [wr][col within tile]

  const int b = blockIdx.x;
  const int q = WEDGE * (b & 7) + (b >> 3);
  int ti, tj;
  pair_from_q(q, ti, tj);
  const int iBase = ti * BM, jBase = tj * BN;
  const bool diag = (ti == tj);

  const int tid = threadIdx.x;
  const int lane = tid & 63;
  const int wave = tid >> 6;
  const int wr = wave >> 1, wc = wave & 1;
  const int n = lane & 31, hi = lane >> 5;

  // per-lane swizzled fragment offset within a 2048B block (s=0 half; s=1 is ^16)
  const unsigned o0 =
      (unsigned)(n * 64 + hi * 32) ^ ((unsigned)((n >> 1) & 7) << 4);

  // staging: per K-step, 16 linear 1KB chunks; wave w owns chunks w*4..w*4+3.
  // chunks 0..7 = A frag-blocks (fb = id>>1, half = id&1); 8..15 = B.
  // BK=128: each wave stages its 4 chunks for BOTH sub-K-steps (8 gload_lds).
  const unsigned char* gsrc[4];
  unsigned ldst[4];
#pragma unroll
  for (int j = 0; j < 4; ++j) {
    const int id = wave * 4 + j;
    const int mat = id >> 3;
    const int fb = (id & 7) >> 1;
    const int rb = (mat ? (jBase >> 5) : (iBase >> 5)) + fb;
    gsrc[j] = e8 + (size_t)(rb * 8) * 2048 + (id & 1) * 1024 + lane * 16;
    ldst[j] = (unsigned)id * 1024 + lane * 16;
  }

  auto STAGE2 = [&](int TT, int buf) {  // stages K-steps 2*TT and 2*TT+1
#pragma unroll
    for (int s = 0; s < 2; ++s)
#pragma unroll
      for (int j = 0; j < 4; ++j)
        __builtin_amdgcn_global_load_lds(
            (const __attribute__((address_space(1))) unsigned int*)(
                gsrc[j] + (size_t)(2 * TT + s) * 2048),
            (__attribute__((address_space(3))) unsigned int*)(
                &lds[buf][s][ldst[j]]),
            16, 0, 0);
  };

  // hoist j-side labels: latency hides under the whole K-loop
  int lj[2];
#pragma unroll
  for (int c = 0; c < 2; ++c) lj[c] = labels[jBase + wc * 64 + c * 32 + n];

  f32x16 acc[2][2];
#pragma unroll
  for (int t = 0; t < 2; ++t)
#pragma unroll
    for (int c = 0; c < 2; ++c) acc[t][c] = (f32x16)0.0f;

  STAGE2(0, 0);
  __syncthreads();
#pragma unroll
  for (int TT = 0; TT < NKP; ++TT) {
    const int cur = TT & 1;
    if (TT + 1 < NKP) STAGE2(TT + 1, cur ^ 1);
#pragma unroll
    for (int s = 0; s < 2; ++s) {
      union { i32x8 v; int4 q2[2]; } aF[2], bF[2];
#pragma unroll
      for (int t = 0; t < 2; ++t) {
        const unsigned char* ab = &lds[cur][s][(wr * 2 + t) * 2048];
        aF[t].q2[0] = *(const int4*)(ab + o0);
        aF[t].q2[1] = *(const int4*)(ab + (o0 ^ 16));
        const unsigned char* bb = &lds[cur][s][8192 + (wc * 2 + t) * 2048];
        bF[t].q2[0] = *(const int4*)(bb + o0);
        bF[t].q2[1] = *(const int4*)(bb + (o0 ^ 16));
      }
#pragma unroll
      for (int t = 0; t < 2; ++t)
#pragma unroll
        for (int c = 0; c < 2; ++c)
          acc[t][c] = __builtin_amdgcn_mfma_scale_f32_32x32x64_f8f6f4(
              aF[t].v, bF[c].v, acc[t][c], 0, 0, /*fp8 A, fp8 B*/
              0, 127, 0, 127);                   /* E8M0 scale = 2^0 */
    }
    __syncthreads();
  }

  // ---- epilogue: batch-hard mining on RAW acc (scale deferred, exact pow2) --
  // 32x32 C/D layout: col = c*32 + (lane&31); row = (r&3) + 8*(r>>2) + 4*hi
  unsigned colAcc[2] = {INF2, INF2};

#pragma unroll
  for (int t = 0; t < 2; ++t) {
    int li[16];
#pragma unroll
    for (int a = 0; a < 4; ++a) {
      int4 v = *(const int4*)(labels + iBase + wr * 64 + t * 32 + 4 * hi + 8 * a);
      li[4 * a + 0] = v.x; li[4 * a + 1] = v.y;
      li[4 * a + 2] = v.z; li[4 * a + 3] = v.w;
    }
    unsigned P[2][16];
#pragma unroll
    for (int c = 0; c < 2; ++c) {
#pragma unroll
      for (int r = 0; r < 16; ++r) {
        const float s = acc[t][c][r];
        const unsigned u = cvtpk(s, -s);  // (pos-candidate, neg-candidate)
        const bool same = (li[r] == lj[c]);
        const unsigned sel = same ? 0x0000FFFFu : 0xFFFF0000u;
        unsigned p = (sel & u) | (~sel & INF2);  // v_bfi_b32
        if (diag) {
          const int row32 = (r & 3) + 8 * (r >> 2) + 4 * hi;
          const bool self =
              (wr * 64 + t * 32 + row32) == (wc * 64 + c * 32 + n);
          p = self ? INF2 : p;  // exclude self (singleton rows -> +inf -> 0)
        }
        P[c][r] = p;
      }
      if (!diag) {  // col-side (transpose) partial: reduce over this t's rows
        unsigned cm = P[c][0];
#pragma unroll
        for (int r = 1; r < 16; ++r) cm = pkmin(cm, P[c][r]);
        colAcc[c] = pkmin(colAcc[c], cm);
      }
    }
    // row-side: fold col-tiles, then 5-stage reg/lane merge-reduce over 32
    // cols. Butterfly exchanges via ds_swizzle (xor within 32-lane group;
    // single instruction, no per-call address setup).
    unsigned m[16];
#pragma unroll
    for (int r = 0; r < 16; ++r) m[r] = pkmin(P[0][r], P[1][r]);
    unsigned w8[8];
#pragma unroll
    for (int i = 0; i < 8; ++i) {
      unsigned x = pkmin(m[2 * i],
          (unsigned)__builtin_amdgcn_ds_swizzle((int)m[2 * i], 0x401F));
      unsigned y = pkmin(m[2 * i + 1],
          (unsigned)__builtin_amdgcn_ds_swizzle((int)m[2 * i + 1], 0x401F));
      w8[i] = (lane & 16) ? y : x;
    }
    unsigned w4[4];
#pragma unroll
    for (int i = 0; i < 4; ++i) {
      unsigned x = pkmin(w8[2 * i],
          (unsigned)__builtin_amdgcn_ds_swizzle((int)w8[2 * i], 0x201F));
      unsigned y = pkmin(w8[2 * i + 1],
          (unsigned)__builtin_amdgcn_ds_swizzle((int)w8[2 * i + 1], 0x201F));
      w4[i] = (lane & 8) ? y : x;
    }
    unsigned w2[2];
#pragma unroll
    for (int i = 0; i < 2; ++i) {
      unsigned x = pkmin(w4[2 * i],
          (unsigned)__builtin_amdgcn_ds_swizzle((int)w4[2 * i], 0x101F));
      unsigned y = pkmin(w4[2 * i + 1],
          (unsigned)__builtin_amdgcn_ds_swizzle((int)w4[2 * i + 1], 0x101F));
      w2[i] = (lane & 4) ? y : x;
    }
    unsigned x1 = pkmin(w2[0],
        (unsigned)__builtin_amdgcn_ds_swizzle((int)w2[0], 0x081F));
    unsigned y1 = pkmin(w2[1],
        (unsigned)__builtin_amdgcn_ds_swizzle((int)w2[1], 0x081F));
    unsigned w1 = (lane & 2) ? y1 : x1;
    w1 = pkmin(w1, (unsigned)__builtin_amdgcn_ds_swizzle((int)w1, 0x041F));
    // chain index rr = 8*b1+4*b2+2*b3+b4 -> row32 = 16*b1+8*b2+4*hi+2*b3+b4
    const int row32 = 16 * ((lane >> 1) & 1) + 8 * ((lane >> 2) & 1) + 4 * hi +
                      2 * ((lane >> 3) & 1) + ((lane >> 4) & 1);
    if ((lane & 1) == 0) bufR[wc][wr * 64 + t * 32 + row32] = w1;
  }

  if (!diag) {
#pragma unroll
    for (int c = 0; c < 2; ++c)
      colAcc[c] = pkmin(colAcc[c], __shfl_xor(colAcc[c], 32, 64));
    if (hi == 0) {
#pragma unroll
      for (int c = 0; c < 2; ++c)
        bufC[wr][wc * 64 + c * 32 + n] = colAcc[c];
    }
  }

  __syncthreads();

  // merge duplicates; one non-atomic store per slot (slot owner = this pair).
  // scr is TRANSPOSED: scr[tile*8192 + row] -> contiguous 512B per wave store
  // (the old row*64+tile layout touched 64 cache lines per wave: 28 MB
  // WRITE_SIZE for 2 MB of data).
  if (wc == 0) {  // waves 0,2: rows wr*64 + lane
    const int row = wr * 64 + lane;
    scr[(unsigned)tj * 8192 + iBase + row] = pkmin(bufR[0][row], bufR[1][row]);
  }
  if (!diag && wr == 0) {  // waves 0,1: cols wc*64 + lane
    const int col = wc * 64 + lane;
    scr[(unsigned)ti * 8192 + jBase + col] = pkmin(bufC[0][col], bufC[1][col]);
  }
}

// ---- kernel 3: per-row packed reduce over 64 slots, then mean of relu ----
// scr[t*8192 + row]: lane-coalesced reads (adjacent lanes, adjacent rows).
__global__ __launch_bounds__(256) void finalize_loss(
    const unsigned* __restrict__ scr, float* __restrict__ out) {
  const int row = blockIdx.x * 256 + threadIdx.x;
  unsigned mm = INF2;
#pragma unroll
  for (int t = 0; t < 64; ++t)
    mm = pkmin(mm, scr[(unsigned)t * 8192 + row]);
  const float mn = __half2float(__ushort_as_half((unsigned short)(mm & 0xffff)));
  const float nmx = __half2float(__ushort_as_half((unsigned short)(mm >> 16)));
  // loss = (max_neg_sim - min_pos_sim)/ESCALE^2 + margin; relu(-inf) = 0
  float loss = (-nmx - mn) * INV_SC2 + MARGIN;
  float sum = loss > 0.f ? loss : 0.f;
#pragma unroll
  for (int m = 1; m < 64; m <<= 1) sum += __shfl_xor(sum, m, 64);
  __shared__ float ws4[4];
  const int lane = threadIdx.x & 63, wave = threadIdx.x >> 6;
  if (lane == 0) ws4[wave] = sum;
  __syncthreads();
  if (threadIdx.x == 0)
    atomicAdd(out, (ws4[0] + ws4[1] + ws4[2] + ws4[3]) * (1.0f / N));
}

extern "C" void kernel_launch(void* const* d_in, const int* in_sizes, int n_in,
                              void* d_out, int out_size, void* d_ws, size_t ws_size,
                              hipStream_t stream) {
  const float* emb = (const float*)d_in[0];
  const int* labels = (const int*)d_in[1];
  float* out = (float*)d_out;

  unsigned char* e8 = (unsigned char*)d_ws;                          // [0, 4 MB)
  unsigned* scr = (unsigned*)((char*)d_ws + (size_t)4 * 1024 * 1024); // [4, 6 MB)

  normalize_rows<<<N / 4, 256, 0, stream>>>(emb, e8, out);  // also zeroes out[0]
  bh_gemm_sym<<<NPAIR, 256, 0, stream>>>(e8, labels, scr);
  finalize_loss<<<N / 256, 256, 0, stream>>>(scr, out);
}

// Round 11
// 114.120 us; speedup vs baseline: 1.0448x; 1.0448x over previous
//
#include <hip/hip_runtime.h>
#include <hip/hip_fp8.h>
#include <hip/hip_fp16.h>
#include <stdint.h>

#define MARGIN 0.3f

constexpr int N = 8192;
constexpr int D = 512;
constexpr int BM = 128, BN = 128;
constexpr int NKS = D / 64;                   // 8 K-steps of 64
constexpr int NT = N / BM;                    // 64 tiles per side
constexpr int NPAIR = NT * (NT + 1) / 2;      // 2080 unordered tile pairs
constexpr int WEDGE = NPAIR / 8;              // 260 pairs per XCD wedge
constexpr float ESCALE = 16.0f;               // fp8 pre-scale
constexpr float INV_SC2 = 1.0f / (ESCALE * ESCALE);  // exact pow2: defer to finalize

typedef int i32x8 __attribute__((ext_vector_type(8)));
typedef float f32x16 __attribute__((ext_vector_type(16)));
typedef __fp16 h2 __attribute__((ext_vector_type(2)));

constexpr unsigned INF2 = 0x7C007C00u;  // packed f16 (+inf, +inf)

__device__ __forceinline__ unsigned char f2fp8(float f) {
  return __hip_fp8_e4m3(f).__x;  // OCP e4m3fn, RNE+sat
}

// packed-f16 min: lo tracks min(pos-sim), hi tracks min(-neg-sim) == -max(neg-sim)
__device__ __forceinline__ unsigned pkmin(unsigned a, unsigned b) {
  unsigned d;
  asm("v_pk_min_f16 %0, %1, %2" : "=v"(d) : "v"(a), "v"(b));
  return d;
}

__device__ __forceinline__ unsigned cvtpk(float lo, float hi) {
  union { h2 h; unsigned u; } cv;
  cv.h = __builtin_amdgcn_cvt_pkrtz(lo, hi);  // RTZ, monotone => mining-safe
  return cv.u;
}

// Decode pair index q (super-tile-major enumeration of the lower triangle)
// into (ti, tj), ti >= tj. Super-tile = 8x8 tiles; base(SI) = 32*SI^2 + 4*SI.
__device__ __forceinline__ void pair_from_q(int q, int& ti, int& tj) {
  int SI = 0;
  while (32 * (SI + 1) * (SI + 1) + 4 * (SI + 1) <= q) ++SI;
  int r = q - (32 * SI * SI + 4 * SI);
  int i, j, SJ;
  if (r < 64 * SI) {
    SJ = r >> 6;
    int w = r & 63;
    i = w >> 3;
    j = w & 7;
  } else {
    int d = r - 64 * SI;
    SJ = SI;
    i = 0;
    while ((i + 1) * (i + 2) / 2 <= d) ++i;
    j = d - i * (i + 1) / 2;
  }
  ti = SI * 8 + i;
  tj = SJ * 8 + j;
}

// e8 layout: 32-row groups g = row>>5, K-steps T = k>>6 (stored-k; the k
// permutation from normalize's lane packing is row-uniform so dots are
// preserved). Block (g,T) = 2048 B at (g*8+T)*2048. Within a block, byte
// (n=row&31, k'=k&63) lives at
//   ((n*64 + (((k'>>4)&3)<<4)) ^ (((n>>1)&7)<<4)) + (k'&15)
// XOR swizzle spreads wave ds_read_b128 of MFMA fragments across banks;
// global_load_lds copies blocks LINEARLY so the swizzle survives.

// ---- kernel 1: L2-normalize rows -> fp8 e4m3 (x16), swizzled block layout --
__global__ __launch_bounds__(256) void normalize_rows(
    const float* __restrict__ emb, unsigned char* __restrict__ e8,
    float* __restrict__ out) {
  if (blockIdx.x == 0 && threadIdx.x == 0) out[0] = 0.f;
  const int wave = threadIdx.x >> 6, lane = threadIdx.x & 63;
  const int row = blockIdx.x * 4 + wave;
  const float4* src = (const float4*)(emb + (size_t)row * D);
  float4 x0 = src[lane];
  float4 x1 = src[lane + 64];
  float ss = x0.x * x0.x + x0.y * x0.y + x0.z * x0.z + x0.w * x0.w +
             x1.x * x1.x + x1.y * x1.y + x1.z * x1.z + x1.w * x1.w;
#pragma unroll
  for (int m = 1; m < 64; m <<= 1) ss += __shfl_xor(ss, m, 64);
  const float r = rsqrtf(ss) * ESCALE;
  union { unsigned char b[8]; unsigned long long u; } o;
  o.b[0] = f2fp8(x0.x * r); o.b[1] = f2fp8(x0.y * r);
  o.b[2] = f2fp8(x0.z * r); o.b[3] = f2fp8(x0.w * r);
  o.b[4] = f2fp8(x1.x * r); o.b[5] = f2fp8(x1.y * r);
  o.b[6] = f2fp8(x1.z * r); o.b[7] = f2fp8(x1.w * r);
  // stored-k for this thread: k = lane*8 .. +7
  const int n = row & 31;
  const unsigned inner =
      ((unsigned)(n * 64 + ((lane >> 1) & 3) * 16) ^
       ((unsigned)((n >> 1) & 7) << 4)) + (lane & 1) * 8;
  const unsigned off = (unsigned)((row >> 5) * 8 + (lane >> 3)) * 2048 + inner;
  *(unsigned long long*)(e8 + off) = o.u;
}

// ---- kernel 2: MX-fp8 (scale=1) symmetric Gram GEMM + batch-hard mining ----
// 2080 blocks (pair q = 260*(b%8) + b/8, XCD-wedge). LDS double-buffered
// staging via global_load_lds x16B (each fragment fetched once); 32x32x64
// f8f6f4 MFMA at the MX rate; packed-f16 mining epilogue (ds_swizzle
// butterflies — single instr, no addr-VALU setup).
__global__ __launch_bounds__(256, 3) void bh_gemm_sym(
    const unsigned char* __restrict__ e8, const int* __restrict__ labels,
    unsigned* __restrict__ scr) {
  __shared__ unsigned char lds[2][16384];  // [buf][A 8KB | B 8KB]
  __shared__ unsigned bufR[2][128];        // [wc][row within tile]
  __shared__ unsigned bufC[2][128];        // [wr][col within tile]

  const int b = blockIdx.x;
  const int q = WEDGE * (b & 7) + (b >> 3);
  int ti, tj;
  pair_from_q(q, ti, tj);
  const int iBase = ti * BM, jBase = tj * BN;
  const bool diag = (ti == tj);

  const int tid = threadIdx.x;
  const int lane = tid & 63;
  const int wave = tid >> 6;
  const int wr = wave >> 1, wc = wave & 1;
  const int n = lane & 31, hi = lane >> 5;

  // per-lane swizzled fragment offset within a 2048B block (s=0 half; s=1 is ^16)
  const unsigned o0 =
      (unsigned)(n * 64 + hi * 32) ^ ((unsigned)((n >> 1) & 7) << 4);

  // staging: 16 linear 1KB chunks per K-step; wave w owns chunks w*4..w*4+3.
  // chunks 0..7 = A frag-blocks (fb = id>>1, half = id&1); 8..15 = B.
  const unsigned char* gsrc[4];
  unsigned ldst[4];
#pragma unroll
  for (int j = 0; j < 4; ++j) {
    const int id = wave * 4 + j;
    const int mat = id >> 3;
    const int fb = (id & 7) >> 1;
    const int rb = (mat ? (jBase >> 5) : (iBase >> 5)) + fb;
    gsrc[j] = e8 + (size_t)(rb * 8) * 2048 + (id & 1) * 1024 + lane * 16;
    ldst[j] = (unsigned)id * 1024 + lane * 16;
  }

  auto STAGE = [&](int T, int buf) {
#pragma unroll
    for (int j = 0; j < 4; ++j)
      __builtin_amdgcn_global_load_lds(
          (const __attribute__((address_space(1))) unsigned int*)(gsrc[j] +
                                                                  (size_t)T * 2048),
          (__attribute__((address_space(3))) unsigned int*)(&lds[buf][ldst[j]]),
          16, 0, 0);
  };

  // hoist j-side labels: latency hides under the whole K-loop
  int lj[2];
#pragma unroll
  for (int c = 0; c < 2; ++c) lj[c] = labels[jBase + wc * 64 + c * 32 + n];

  f32x16 acc[2][2];
#pragma unroll
  for (int t = 0; t < 2; ++t)
#pragma unroll
    for (int c = 0; c < 2; ++c) acc[t][c] = (f32x16)0.0f;

  STAGE(0, 0);
  __syncthreads();
#pragma unroll
  for (int T = 0; T < NKS; ++T) {
    const int cur = T & 1;
    if (T + 1 < NKS) STAGE(T + 1, cur ^ 1);
    union { i32x8 v; int4 q2[2]; } aF[2], bF[2];
#pragma unroll
    for (int t = 0; t < 2; ++t) {
      const unsigned char* ab = &lds[cur][(wr * 2 + t) * 2048];
      aF[t].q2[0] = *(const int4*)(ab + o0);
      aF[t].q2[1] = *(const int4*)(ab + (o0 ^ 16));
      const unsigned char* bb = &lds[cur][8192 + (wc * 2 + t) * 2048];
      bF[t].q2[0] = *(const int4*)(bb + o0);
      bF[t].q2[1] = *(const int4*)(bb + (o0 ^ 16));
    }
#pragma unroll
    for (int t = 0; t < 2; ++t)
#pragma unroll
      for (int c = 0; c < 2; ++c)
        acc[t][c] = __builtin_amdgcn_mfma_scale_f32_32x32x64_f8f6f4(
            aF[t].v, bF[c].v, acc[t][c], 0, 0, /*fp8 A, fp8 B*/
            0, 127, 0, 127);                   /* E8M0 scale = 2^0 */
    __syncthreads();
  }

  // ---- epilogue: batch-hard mining on RAW acc (scale deferred, exact pow2) --
  // 32x32 C/D layout: col = c*32 + (lane&31); row = (r&3) + 8*(r>>2) + 4*hi
  unsigned colAcc[2] = {INF2, INF2};

#pragma unroll
  for (int t = 0; t < 2; ++t) {
    int li[16];
#pragma unroll
    for (int a = 0; a < 4; ++a) {
      int4 v = *(const int4*)(labels + iBase + wr * 64 + t * 32 + 4 * hi + 8 * a);
      li[4 * a + 0] = v.x; li[4 * a + 1] = v.y;
      li[4 * a + 2] = v.z; li[4 * a + 3] = v.w;
    }
    unsigned P[2][16];
#pragma unroll
    for (int c = 0; c < 2; ++c) {
#pragma unroll
      for (int r = 0; r < 16; ++r) {
        const float s = acc[t][c][r];
        const unsigned u = cvtpk(s, -s);  // (pos-candidate, neg-candidate)
        const bool same = (li[r] == lj[c]);
        const unsigned sel = same ? 0x0000FFFFu : 0xFFFF0000u;
        unsigned p = (sel & u) | (~sel & INF2);  // v_bfi_b32
        if (diag) {
          const int row32 = (r & 3) + 8 * (r >> 2) + 4 * hi;
          const bool self =
              (wr * 64 + t * 32 + row32) == (wc * 64 + c * 32 + n);
          p = self ? INF2 : p;  // exclude self (singleton rows -> +inf -> 0)
        }
        P[c][r] = p;
      }
      if (!diag) {  // col-side (transpose) partial: reduce over this t's rows
        unsigned cm = P[c][0];
#pragma unroll
        for (int r = 1; r < 16; ++r) cm = pkmin(cm, P[c][r]);
        colAcc[c] = pkmin(colAcc[c], cm);
      }
    }
    // row-side: fold col-tiles, then 5-stage reg/lane merge-reduce over 32
    // cols. Butterfly exchanges via ds_swizzle (xor within 32-lane group;
    // single instruction, no per-call address setup).
    unsigned m[16];
#pragma unroll
    for (int r = 0; r < 16; ++r) m[r] = pkmin(P[0][r], P[1][r]);
    unsigned w8[8];
#pragma unroll
    for (int i = 0; i < 8; ++i) {
      unsigned x = pkmin(m[2 * i],
          (unsigned)__builtin_amdgcn_ds_swizzle((int)m[2 * i], 0x401F));
      unsigned y = pkmin(m[2 * i + 1],
          (unsigned)__builtin_amdgcn_ds_swizzle((int)m[2 * i + 1], 0x401F));
      w8[i] = (lane & 16) ? y : x;
    }
    unsigned w4[4];
#pragma unroll
    for (int i = 0; i < 4; ++i) {
      unsigned x = pkmin(w8[2 * i],
          (unsigned)__builtin_amdgcn_ds_swizzle((int)w8[2 * i], 0x201F));
      unsigned y = pkmin(w8[2 * i + 1],
          (unsigned)__builtin_amdgcn_ds_swizzle((int)w8[2 * i + 1], 0x201F));
      w4[i] = (lane & 8) ? y : x;
    }
    unsigned w2[2];
#pragma unroll
    for (int i = 0; i < 2; ++i) {
      unsigned x = pkmin(w4[2 * i],
          (unsigned)__builtin_amdgcn_ds_swizzle((int)w4[2 * i], 0x101F));
      unsigned y = pkmin(w4[2 * i + 1],
          (unsigned)__builtin_amdgcn_ds_swizzle((int)w4[2 * i + 1], 0x101F));
      w2[i] = (lane & 4) ? y : x;
    }
    unsigned x1 = pkmin(w2[0],
        (unsigned)__builtin_amdgcn_ds_swizzle((int)w2[0], 0x081F));
    unsigned y1 = pkmin(w2[1],
        (unsigned)__builtin_amdgcn_ds_swizzle((int)w2[1], 0x081F));
    unsigned w1 = (lane & 2) ? y1 : x1;
    w1 = pkmin(w1, (unsigned)__builtin_amdgcn_ds_swizzle((int)w1, 0x041F));
    // chain index rr = 8*b1+4*b2+2*b3+b4 -> row32 = 16*b1+8*b2+4*hi+2*b3+b4
    const int row32 = 16 * ((lane >> 1) & 1) + 8 * ((lane >> 2) & 1) + 4 * hi +
                      2 * ((lane >> 3) & 1) + ((lane >> 4) & 1);
    if ((lane & 1) == 0) bufR[wc][wr * 64 + t * 32 + row32] = w1;
  }

  if (!diag) {
#pragma unroll
    for (int c = 0; c < 2; ++c)
      colAcc[c] = pkmin(colAcc[c], __shfl_xor(colAcc[c], 32, 64));
    if (hi == 0) {
#pragma unroll
      for (int c = 0; c < 2; ++c)
        bufC[wr][wc * 64 + c * 32 + n] = colAcc[c];
    }
  }

  __syncthreads();

  // merge duplicates; one non-atomic store per slot (slot owner = this pair).
  // scr is TRANSPOSED: scr[tile*8192 + row] -> each wave stores a contiguous
  // 512B run (2 cache lines) instead of 64 partial lines (r7 counters showed
  // 28 MB WRITE_SIZE for 2 MB of scr data with the row*64+tile layout).
  if (wc == 0) {  // waves 0,2: rows wr*64 + lane
    const int row = wr * 64 + lane;
    scr[(unsigned)tj * 8192 + iBase + row] = pkmin(bufR[0][row], bufR[1][row]);
  }
  if (!diag && wr == 0) {  // waves 0,1: cols wc*64 + lane
    const int col = wc * 64 + lane;
    scr[(unsigned)ti * 8192 + jBase + col] = pkmin(bufC[0][col], bufC[1][col]);
  }
}

// ---- kernel 3: per-row packed reduce over 64 slots, then mean of relu ----
// scr[t*8192 + row]: lane-coalesced reads (adjacent lanes, adjacent rows).
__global__ __launch_bounds__(256) void finalize_loss(
    const unsigned* __restrict__ scr, float* __restrict__ out) {
  const int row = blockIdx.x * 256 + threadIdx.x;
  unsigned mm = INF2;
#pragma unroll
  for (int t = 0; t < 64; ++t)
    mm = pkmin(mm, scr[(unsigned)t * 8192 + row]);
  const float mn = __half2float(__ushort_as_half((unsigned short)(mm & 0xffff)));
  const float nmx = __half2float(__ushort_as_half((unsigned short)(mm >> 16)));
  // loss = (max_neg_sim - min_pos_sim)/ESCALE^2 + margin; relu(-inf) = 0
  float loss = (-nmx - mn) * INV_SC2 + MARGIN;
  float sum = loss > 0.f ? loss : 0.f;
#pragma unroll
  for (int m = 1; m < 64; m <<= 1) sum += __shfl_xor(sum, m, 64);
  __shared__ float ws4[4];
  const int lane = threadIdx.x & 63, wave = threadIdx.x >> 6;
  if (lane == 0) ws4[wave] = sum;
  __syncthreads();
  if (threadIdx.x == 0)
    atomicAdd(out, (ws4[0] + ws4[1] + ws4[2] + ws4[3]) * (1.0f / N));
}

extern "C" void kernel_launch(void* const* d_in, const int* in_sizes, int n_in,
                              void* d_out, int out_size, void* d_ws, size_t ws_size,
                              hipStream_t stream) {
  const float* emb = (const float*)d_in[0];
  const int* labels = (const int*)d_in[1];
  float* out = (float*)d_out;

  unsigned char* e8 = (unsigned char*)d_ws;                          // [0, 4 MB)
  unsigned* scr = (unsigned*)((char*)d_ws + (size_t)4 * 1024 * 1024); // [4, 6 MB)

  normalize_rows<<<N / 4, 256, 0, stream>>>(emb, e8, out);  // also zeroes out[0]
  bh_gemm_sym<<<NPAIR, 256, 0, stream>>>(e8, labels, scr);
  finalize_loss<<<N / 256, 256, 0, stream>>>(scr, out);
}

// Round 12
// 101.887 us; speedup vs baseline: 1.1702x; 1.1201x over previous
//
#include <hip/hip_runtime.h>
#include <hip/hip_fp8.h>
#include <hip/hip_fp16.h>
#include <stdint.h>

#define MARGIN 0.3f

constexpr int N = 8192;
constexpr int D = 512;
constexpr int BM = 128, BN = 128;
constexpr int NKS = D / 64;                   // 8 K-steps of 64
constexpr int NT = N / BM;                    // 64 tiles per side
constexpr int NPAIR = NT * (NT + 1) / 2;      // 2080 unordered tile pairs
constexpr int WEDGE = NPAIR / 8;              // 260 pairs per XCD wedge
constexpr float ESCALE = 16.0f;               // fp8 pre-scale
constexpr float INV_SC2 = 1.0f / (ESCALE * ESCALE);  // exact pow2: defer to finalize

typedef int i32x8 __attribute__((ext_vector_type(8)));
typedef float f32x16 __attribute__((ext_vector_type(16)));
typedef __fp16 h2 __attribute__((ext_vector_type(2)));

constexpr unsigned INF2 = 0x7C007C00u;  // packed f16 (+inf, +inf)

__device__ __forceinline__ unsigned char f2fp8(float f) {
  return __hip_fp8_e4m3(f).__x;  // OCP e4m3fn, RNE+sat
}

// packed-f16 min: lo tracks min(pos-sim), hi tracks min(-neg-sim) == -max(neg-sim)
__device__ __forceinline__ unsigned pkmin(unsigned a, unsigned b) {
  unsigned d;
  asm("v_pk_min_f16 %0, %1, %2" : "=v"(d) : "v"(a), "v"(b));
  return d;
}

__device__ __forceinline__ unsigned cvtpk(float lo, float hi) {
  union { h2 h; unsigned u; } cv;
  cv.h = __builtin_amdgcn_cvt_pkrtz(lo, hi);  // RTZ, monotone => mining-safe
  return cv.u;
}

// Decode pair index q (super-tile-major enumeration of the lower triangle)
// into (ti, tj), ti >= tj. Super-tile = 8x8 tiles; base(SI) = 32*SI^2 + 4*SI.
__device__ __forceinline__ void pair_from_q(int q, int& ti, int& tj) {
  int SI = 0;
  while (32 * (SI + 1) * (SI + 1) + 4 * (SI + 1) <= q) ++SI;
  int r = q - (32 * SI * SI + 4 * SI);
  int i, j, SJ;
  if (r < 64 * SI) {
    SJ = r >> 6;
    int w = r & 63;
    i = w >> 3;
    j = w & 7;
  } else {
    int d = r - 64 * SI;
    SJ = SI;
    i = 0;
    while ((i + 1) * (i + 2) / 2 <= d) ++i;
    j = d - i * (i + 1) / 2;
  }
  ti = SI * 8 + i;
  tj = SJ * 8 + j;
}

// e8 layout: 32-row groups g = row>>5, K-steps T = k>>6 (stored-k; the k
// permutation from normalize's lane packing is row-uniform so dots are
// preserved). Block (g,T) = 2048 B at (g*8+T)*2048. Within a block, byte
// (n=row&31, k'=k&63) lives at
//   ((n*64 + (((k'>>4)&3)<<4)) ^ (((n>>1)&7)<<4)) + (k'&15)
// XOR swizzle spreads wave ds_read_b128 of MFMA fragments across banks;
// global_load_lds copies blocks LINEARLY so the swizzle survives.

// ---- kernel 1: L2-normalize rows -> fp8 e4m3 (x16), swizzled block layout --
__global__ __launch_bounds__(256) void normalize_rows(
    const float* __restrict__ emb, unsigned char* __restrict__ e8,
    float* __restrict__ out) {
  if (blockIdx.x == 0 && threadIdx.x == 0) out[0] = 0.f;
  const int wave = threadIdx.x >> 6, lane = threadIdx.x & 63;
  const int row = blockIdx.x * 4 + wave;
  const float4* src = (const float4*)(emb + (size_t)row * D);
  float4 x0 = src[lane];
  float4 x1 = src[lane + 64];
  float ss = x0.x * x0.x + x0.y * x0.y + x0.z * x0.z + x0.w * x0.w +
             x1.x * x1.x + x1.y * x1.y + x1.z * x1.z + x1.w * x1.w;
#pragma unroll
  for (int m = 1; m < 64; m <<= 1) ss += __shfl_xor(ss, m, 64);
  const float r = rsqrtf(ss) * ESCALE;
  union { unsigned char b[8]; unsigned long long u; } o;
  o.b[0] = f2fp8(x0.x * r); o.b[1] = f2fp8(x0.y * r);
  o.b[2] = f2fp8(x0.z * r); o.b[3] = f2fp8(x0.w * r);
  o.b[4] = f2fp8(x1.x * r); o.b[5] = f2fp8(x1.y * r);
  o.b[6] = f2fp8(x1.z * r); o.b[7] = f2fp8(x1.w * r);
  // stored-k for this thread: k = lane*8 .. +7
  const int n = row & 31;
  const unsigned inner =
      ((unsigned)(n * 64 + ((lane >> 1) & 3) * 16) ^
       ((unsigned)((n >> 1) & 7) << 4)) + (lane & 1) * 8;
  const unsigned off = (unsigned)((row >> 5) * 8 + (lane >> 3)) * 2048 + inner;
  // non-temporal: land clean in L3, not dirty in this XCD's L2 (gemm reads
  // from all 8 XCDs; dirty-remote-L2 first touches pay snoop latency)
  __builtin_nontemporal_store(o.u, (unsigned long long*)(e8 + off));
}

// ---- kernel 2: MX-fp8 (scale=1) symmetric Gram GEMM + batch-hard mining ----
// 2080 blocks (pair q = 260*(b%8) + b/8, XCD-wedge). LDS double-buffered
// staging via global_load_lds x16B (each fragment fetched once); 32x32x64
// f8f6f4 MFMA at the MX rate; packed-f16 mining epilogue (ds_swizzle
// butterflies — single instr, no addr-VALU setup).
__global__ __launch_bounds__(256, 3) void bh_gemm_sym(
    const unsigned char* __restrict__ e8, const int* __restrict__ labels,
    unsigned* __restrict__ scr) {
  __shared__ unsigned char lds[2][16384];  // [buf][A 8KB | B 8KB]
  __shared__ unsigned bufR[2][128];        // [wc][row within tile]
  __shared__ unsigned bufC[2][128];        // [wr][col within tile]

  const int b = blockIdx.x;
  const int q = WEDGE * (b & 7) + (b >> 3);
  int ti, tj;
  pair_from_q(q, ti, tj);
  const int iBase = ti * BM, jBase = tj * BN;
  const bool diag = (ti == tj);

  const int tid = threadIdx.x;
  const int lane = tid & 63;
  const int wave = tid >> 6;
  const int wr = wave >> 1, wc = wave & 1;
  const int n = lane & 31, hi = lane >> 5;

  // per-lane swizzled fragment offset within a 2048B block (s=0 half; s=1 is ^16)
  const unsigned o0 =
      (unsigned)(n * 64 + hi * 32) ^ ((unsigned)((n >> 1) & 7) << 4);

  // staging: 16 linear 1KB chunks per K-step; wave w owns chunks w*4..w*4+3.
  // chunks 0..7 = A frag-blocks (fb = id>>1, half = id&1); 8..15 = B.
  const unsigned char* gsrc[4];
  unsigned ldst[4];
#pragma unroll
  for (int j = 0; j < 4; ++j) {
    const int id = wave * 4 + j;
    const int mat = id >> 3;
    const int fb = (id & 7) >> 1;
    const int rb = (mat ? (jBase >> 5) : (iBase >> 5)) + fb;
    gsrc[j] = e8 + (size_t)(rb * 8) * 2048 + (id & 1) * 1024 + lane * 16;
    ldst[j] = (unsigned)id * 1024 + lane * 16;
  }

  auto STAGE = [&](int T, int buf) {
#pragma unroll
    for (int j = 0; j < 4; ++j)
      __builtin_amdgcn_global_load_lds(
          (const __attribute__((address_space(1))) unsigned int*)(gsrc[j] +
                                                                  (size_t)T * 2048),
          (__attribute__((address_space(3))) unsigned int*)(&lds[buf][ldst[j]]),
          16, 0, 0);
  };

  // hoist j-side labels: latency hides under the whole K-loop
  int lj[2];
#pragma unroll
  for (int c = 0; c < 2; ++c) lj[c] = labels[jBase + wc * 64 + c * 32 + n];

  f32x16 acc[2][2];
#pragma unroll
  for (int t = 0; t < 2; ++t)
#pragma unroll
    for (int c = 0; c < 2; ++c) acc[t][c] = (f32x16)0.0f;

  STAGE(0, 0);
  __syncthreads();
#pragma unroll
  for (int T = 0; T < NKS; ++T) {
    const int cur = T & 1;
    if (T + 1 < NKS) STAGE(T + 1, cur ^ 1);
    union { i32x8 v; int4 q2[2]; } aF[2], bF[2];
#pragma unroll
    for (int t = 0; t < 2; ++t) {
      const unsigned char* ab = &lds[cur][(wr * 2 + t) * 2048];
      aF[t].q2[0] = *(const int4*)(ab + o0);
      aF[t].q2[1] = *(const int4*)(ab + (o0 ^ 16));
      const unsigned char* bb = &lds[cur][8192 + (wc * 2 + t) * 2048];
      bF[t].q2[0] = *(const int4*)(bb + o0);
      bF[t].q2[1] = *(const int4*)(bb + (o0 ^ 16));
    }
#pragma unroll
    for (int t = 0; t < 2; ++t)
#pragma unroll
      for (int c = 0; c < 2; ++c)
        acc[t][c] = __builtin_amdgcn_mfma_scale_f32_32x32x64_f8f6f4(
            aF[t].v, bF[c].v, acc[t][c], 0, 0, /*fp8 A, fp8 B*/
            0, 127, 0, 127);                   /* E8M0 scale = 2^0 */
    __syncthreads();
  }

  // ---- epilogue: batch-hard mining on RAW acc (scale deferred, exact pow2) --
  // 32x32 C/D layout: col = c*32 + (lane&31); row = (r&3) + 8*(r>>2) + 4*hi
  unsigned colAcc[2] = {INF2, INF2};

#pragma unroll
  for (int t = 0; t < 2; ++t) {
    int li[16];
#pragma unroll
    for (int a = 0; a < 4; ++a) {
      int4 v = *(const int4*)(labels + iBase + wr * 64 + t * 32 + 4 * hi + 8 * a);
      li[4 * a + 0] = v.x; li[4 * a + 1] = v.y;
      li[4 * a + 2] = v.z; li[4 * a + 3] = v.w;
    }
    unsigned P[2][16];
#pragma unroll
    for (int c = 0; c < 2; ++c) {
#pragma unroll
      for (int r = 0; r < 16; ++r) {
        const float s = acc[t][c][r];
        const unsigned u = cvtpk(s, -s);  // (pos-candidate, neg-candidate)
        const bool same = (li[r] == lj[c]);
        const unsigned sel = same ? 0x0000FFFFu : 0xFFFF0000u;
        unsigned p = (sel & u) | (~sel & INF2);  // v_bfi_b32
        if (diag) {
          const int row32 = (r & 3) + 8 * (r >> 2) + 4 * hi;
          const bool self =
              (wr * 64 + t * 32 + row32) == (wc * 64 + c * 32 + n);
          p = self ? INF2 : p;  // exclude self (singleton rows -> +inf -> 0)
        }
        P[c][r] = p;
      }
      if (!diag) {  // col-side (transpose) partial: reduce over this t's rows
        unsigned cm = P[c][0];
#pragma unroll
        for (int r = 1; r < 16; ++r) cm = pkmin(cm, P[c][r]);
        colAcc[c] = pkmin(colAcc[c], cm);
      }
    }
    // row-side: fold col-tiles, then 5-stage reg/lane merge-reduce over 32
    // cols. Butterfly exchanges via ds_swizzle (xor within 32-lane group;
    // single instruction, no per-call address setup).
    unsigned m[16];
#pragma unroll
    for (int r = 0; r < 16; ++r) m[r] = pkmin(P[0][r], P[1][r]);
    unsigned w8[8];
#pragma unroll
    for (int i = 0; i < 8; ++i) {
      unsigned x = pkmin(m[2 * i],
          (unsigned)__builtin_amdgcn_ds_swizzle((int)m[2 * i], 0x401F));
      unsigned y = pkmin(m[2 * i + 1],
          (unsigned)__builtin_amdgcn_ds_swizzle((int)m[2 * i + 1], 0x401F));
      w8[i] = (lane & 16) ? y : x;
    }
    unsigned w4[4];
#pragma unroll
    for (int i = 0; i < 4; ++i) {
      unsigned x = pkmin(w8[2 * i],
          (unsigned)__builtin_amdgcn_ds_swizzle((int)w8[2 * i], 0x201F));
      unsigned y = pkmin(w8[2 * i + 1],
          (unsigned)__builtin_amdgcn_ds_swizzle((int)w8[2 * i + 1], 0x201F));
      w4[i] = (lane & 8) ? y : x;
    }
    unsigned w2[2];
#pragma unroll
    for (int i = 0; i < 2; ++i) {
      unsigned x = pkmin(w4[2 * i],
          (unsigned)__builtin_amdgcn_ds_swizzle((int)w4[2 * i], 0x101F));
      unsigned y = pkmin(w4[2 * i + 1],
          (unsigned)__builtin_amdgcn_ds_swizzle((int)w4[2 * i + 1], 0x101F));
      w2[i] = (lane & 4) ? y : x;
    }
    unsigned x1 = pkmin(w2[0],
        (unsigned)__builtin_amdgcn_ds_swizzle((int)w2[0], 0x081F));
    unsigned y1 = pkmin(w2[1],
        (unsigned)__builtin_amdgcn_ds_swizzle((int)w2[1], 0x081F));
    unsigned w1 = (lane & 2) ? y1 : x1;
    w1 = pkmin(w1, (unsigned)__builtin_amdgcn_ds_swizzle((int)w1, 0x041F));
    // chain index rr = 8*b1+4*b2+2*b3+b4 -> row32 = 16*b1+8*b2+4*hi+2*b3+b4
    const int row32 = 16 * ((lane >> 1) & 1) + 8 * ((lane >> 2) & 1) + 4 * hi +
                      2 * ((lane >> 3) & 1) + ((lane >> 4) & 1);
    if ((lane & 1) == 0) bufR[wc][wr * 64 + t * 32 + row32] = w1;
  }

  if (!diag) {
#pragma unroll
    for (int c = 0; c < 2; ++c)
      colAcc[c] = pkmin(colAcc[c], __shfl_xor(colAcc[c], 32, 64));
    if (hi == 0) {
#pragma unroll
      for (int c = 0; c < 2; ++c)
        bufC[wr][wc * 64 + c * 32 + n] = colAcc[c];
    }
  }

  __syncthreads();

  // merge duplicates; one non-atomic store per slot (slot owner = this pair)
  if (wc == 0) {  // waves 0,2: rows wr*64 + lane
    const int row = wr * 64 + lane;
    __builtin_nontemporal_store(pkmin(bufR[0][row], bufR[1][row]),
                                &scr[(unsigned)(iBase + row) * 64 + tj]);
  }
  if (!diag && wr == 0) {  // waves 0,1: cols wc*64 + lane
    const int col = wc * 64 + lane;
    __builtin_nontemporal_store(pkmin(bufC[0][col], bufC[1][col]),
                                &scr[(unsigned)(jBase + col) * 64 + ti]);
  }
}

// ---- kernel 3: per-row packed reduce over 64 slots, then mean of relu ----
__global__ __launch_bounds__(256) void finalize_loss(
    const unsigned* __restrict__ scr, float* __restrict__ out) {
  const int row = blockIdx.x * 256 + threadIdx.x;
  const uint4* p = (const uint4*)(scr + (size_t)row * 64);
  unsigned mm = INF2;
#pragma unroll
  for (int i = 0; i < 16; ++i) {
    uint4 w = p[i];
    mm = pkmin(mm, pkmin(pkmin(w.x, w.y), pkmin(w.z, w.w)));
  }
  const float mn = __half2float(__ushort_as_half((unsigned short)(mm & 0xffff)));
  const float nmx = __half2float(__ushort_as_half((unsigned short)(mm >> 16)));
  // loss = (max_neg_sim - min_pos_sim)/ESCALE^2 + margin; relu(-inf) = 0
  float loss = (-nmx - mn) * INV_SC2 + MARGIN;
  float sum = loss > 0.f ? loss : 0.f;
#pragma unroll
  for (int m = 1; m < 64; m <<= 1) sum += __shfl_xor(sum, m, 64);
  __shared__ float ws4[4];
  const int lane = threadIdx.x & 63, wave = threadIdx.x >> 6;
  if (lane == 0) ws4[wave] = sum;
  __syncthreads();
  if (threadIdx.x == 0)
    atomicAdd(out, (ws4[0] + ws4[1] + ws4[2] + ws4[3]) * (1.0f / N));
}

extern "C" void kernel_launch(void* const* d_in, const int* in_sizes, int n_in,
                              void* d_out, int out_size, void* d_ws, size_t ws_size,
                              hipStream_t stream) {
  const float* emb = (const float*)d_in[0];
  const int* labels = (const int*)d_in[1];
  float* out = (float*)d_out;

  unsigned char* e8 = (unsigned char*)d_ws;                          // [0, 4 MB)
  unsigned* scr = (unsigned*)((char*)d_ws + (size_t)4 * 1024 * 1024); // [4, 6 MB)

  normalize_rows<<<N / 4, 256, 0, stream>>>(emb, e8, out);  // also zeroes out[0]
  bh_gemm_sym<<<NPAIR, 256, 0, stream>>>(e8, labels, scr);
  finalize_loss<<<N / 256, 256, 0, stream>>>(scr, out);
}